// Round 12
// baseline (148.650 us; speedup 1.0000x reference)
//
#include <hip/hip_runtime.h>
#include <math.h>

// Problem constants: B=16, N=131072, NUM_GROUPS=16
#define NPTS_N 131072
#define NGROUP 16
#define NBG 256            // B * NUM_GROUPS (select sub-blocks)
#define CBLK 512           // compact blocks (32 per batch) [R8-proven geometry]
#define BPB 32             // compact blocks per batch
#define PPB 4096           // points per compact block
#define SEGCAP 256         // per (block,group) segment cap; mean 128, sigma ~11
#define NACC 64            // spread accumulator slots for loss sum
#define LGRID 1024         // loss blocks (2048 pts each); co-resident at 8/CU
#define EPSF 1e-6f

// ---------- LLC coherence-point relaxed helpers (no cache maintenance) ----------
template <typename T>
__device__ __forceinline__ void st_dev(T* p, T v) {
    __hip_atomic_store(p, v, __ATOMIC_RELAXED, __HIP_MEMORY_SCOPE_AGENT);
}
template <typename T>
__device__ __forceinline__ T ld_dev(const T* p) {
    return __hip_atomic_load((T*)p, __ATOMIC_RELAXED, __HIP_MEMORY_SCOPE_AGENT);
}

// ---------- order-preserving float<->uint key ----------
__device__ __forceinline__ unsigned f2key(float f) {
    unsigned u = __float_as_uint(f);
    return (u & 0x80000000u) ? ~u : (u | 0x80000000u);
}
__device__ __forceinline__ float key2f(unsigned k) {
    unsigned u = (k & 0x80000000u) ? (k ^ 0x80000000u) : ~k;
    return __uint_as_float(u);
}
__device__ __forceinline__ float flog1p(float a) {
    return __log2f(1.0f + a) * 0.69314718056f;
}

// ---------- 1) compact valid z-keys + packed mask|group bytes ----------
// 512 blocks x 256 threads; thread = 16 consecutive points. Plain scattered
// stores (cheap; R10: scattered global ATOMICS are ~5x worse). Block 0 inits
// kernel-2 control state (plain stores, visible at the kernel boundary).
__global__ __launch_bounds__(256) void compact_kernel(
        const float* __restrict__ target,
        const int* __restrict__ mask,
        const int* __restrict__ groups,
        unsigned* __restrict__ bucket,
        unsigned* __restrict__ blockCnt,
        unsigned char* __restrict__ packed,
        float* __restrict__ accF,
        unsigned* __restrict__ done,
        unsigned* __restrict__ ctrB) {
    __shared__ unsigned scnt[NGROUP];
    int tid = threadIdx.x, blk = blockIdx.x;
    if (blk == 0) {                       // init for kernel 2
        if (tid < NACC) accF[tid] = 0.f;
        else if (tid == NACC) { *done = 0; *ctrB = 0; }
    }
    int i0 = blk * PPB + tid * 16;
    if (tid < NGROUP) scnt[tid] = 0;
    __syncthreads();
    int4 m[4], g[4];
    #pragma unroll
    for (int k = 0; k < 4; ++k) {
        m[k] = *(const int4*)(mask + i0 + k * 4);
        g[k] = *(const int4*)(groups + i0 + k * 4);
    }
    unsigned pk[4];
    unsigned keys[16]; unsigned meta[16]; unsigned vbits = 0;
    #pragma unroll
    for (int k = 0; k < 4; ++k) {
        int mm[4] = {m[k].x, m[k].y, m[k].z, m[k].w};
        int gg[4] = {g[k].x, g[k].y, g[k].z, g[k].w};
        unsigned pb = 0;
        #pragma unroll
        for (int j = 0; j < 4; ++j) {
            int idx = k * 4 + j;
            unsigned gj = (unsigned)gg[j] & 15u;
            pb |= (gj | (mm[j] ? 0x80u : 0u)) << (8 * j);
            if (mm[j]) {
                keys[idx] = f2key(target[(size_t)(i0 + idx) * 3 + 2]);
                unsigned pos = atomicAdd(&scnt[gj], 1u);   // LDS atomic (cheap)
                meta[idx] = (gj << 16) | pos;
                vbits |= 1u << idx;
            }
        }
        pk[k] = pb;
    }
    *(uint4*)(packed + i0) = make_uint4(pk[0], pk[1], pk[2], pk[3]);
    __syncthreads();
    if (tid < NGROUP) blockCnt[blk * NGROUP + tid] = scnt[tid];  // plain store
    #pragma unroll
    for (int idx = 0; idx < 16; ++idx) {
        if (vbits & (1u << idx)) {
            unsigned gj = meta[idx] >> 16, pos = meta[idx] & 0xFFFFu;
            if (pos < SEGCAP)
                bucket[(size_t)(blk * NGROUP + gj) * SEGCAP + pos] = keys[idx];
        }
    }
}

struct SelSh {                 // LDS-light select state (~8.5 KB total)
    unsigned hist[2048];       // 8 KB
    unsigned sc[BPB];
    unsigned segoff[BPB + 1];
    unsigned wsum[4];
    unsigned sres[2];
};
struct MiscSh {
    float    sinv[NGROUP];
    float    swsum[4];
    float    red[256];
    float    accSum;
    bool     isLast;
};

// ---------- 2) fused select + loss + finalize ----------
// 1024 blocks x 256 threads, __launch_bounds__(256,8): <=64 VGPR, ~8.6 KB LDS
// -> 8 blocks/CU (32 waves) so the latency-bound loss phase keeps R8 occupancy
// (R11 lesson: 33 KB LDS halved residency and doubled loss time).
// Blocks 0..255: 3-pass radix select histogramming DIRECTLY from global bucket
// (L2-cached after the kernel boundary; passes 2-3 hit L2). Publish norm/cnt
// via LLC-point stores + vmcnt drain + ctrB bump; all blocks s_sleep-poll.
__global__ __launch_bounds__(256, 8) void sel_loss_kernel(
        const float* __restrict__ pred,
        const float* __restrict__ target,
        const unsigned char* __restrict__ packed,
        const unsigned* __restrict__ bucket,
        const unsigned* __restrict__ blockCnt,
        unsigned* __restrict__ cnt,
        float* __restrict__ norm,
        float* __restrict__ accF,
        unsigned* __restrict__ done,
        unsigned* __restrict__ ctrB,
        float* __restrict__ out) {
    __shared__ union { SelSh sel; MiscSh misc; } sh;
    int tid = threadIdx.x;
    int blk = blockIdx.x;

    // ================= Phase S: select (blocks 0..255) =================
    if (blk < NBG) {
        int b = blk >> 4, g = blk & 15;
        if (tid < BPB) {
            unsigned s = blockCnt[(b * BPB + tid) * NGROUP + g];
            if (s > SEGCAP) s = SEGCAP;
            sh.sel.sc[tid] = s;
            unsigned inc = s;
            #pragma unroll
            for (int o = 1; o < BPB; o <<= 1) {
                unsigned v = __shfl_up(inc, o, 64);
                if (tid >= o) inc += v;
            }
            sh.sel.segoff[tid + 1] = inc;
            if (tid == 0) sh.sel.segoff[0] = 0;
        }
        __syncthreads();
        unsigned n = sh.sel.segoff[BPB];
        if (tid == 0) st_dev(&cnt[blk], n);
        if (n == 0) {
            if (tid == 0) st_dev(&norm[blk], 1.0f);
        } else {
            unsigned rank = (n - 1) >> 1;     // lower-median rank
            unsigned selkey = 0;
            const int shifts[3] = {21, 10, 0};
            const int widths[3] = {11, 11, 10};
            int wv = tid >> 6, ln = tid & 63;
            for (int p = 0; p < 3; ++p) {
                int sft = shifts[p], w = widths[p];
                unsigned nb = 1u << w, bmask = nb - 1;
                for (unsigned j = tid; j < nb; j += 256) sh.sel.hist[j] = 0;
                __syncthreads();
                // histogram straight from global: wave wv scans segments wv, wv+4, ...
                for (int c = wv; c < BPB; c += 4) {
                    unsigned count = sh.sel.sc[c];
                    const unsigned* src = bucket + (size_t)((b * BPB + c) * NGROUP + g) * SEGCAP;
                    for (unsigned j = ln; j < count; j += 64) {
                        unsigned key = src[j];
                        bool in = (p == 0) || ((key >> (sft + w)) == selkey);
                        if (in) atomicAdd(&sh.sel.hist[(key >> sft) & bmask], 1u);
                    }
                }
                __syncthreads();
                unsigned cpl = nb >> 8;          // bins per thread: 8 or 4
                unsigned basebin = tid * cpl;
                unsigned s = 0;
                for (unsigned j = 0; j < cpl; ++j) s += sh.sel.hist[basebin + j];
                unsigned inc = s;
                #pragma unroll
                for (int o = 1; o < 64; o <<= 1) {
                    unsigned v = __shfl_up(inc, o, 64);
                    if ((tid & 63) >= o) inc += v;
                }
                if ((tid & 63) == 63) sh.sel.wsum[tid >> 6] = inc;
                __syncthreads();
                unsigned woff = 0;
                for (int w2 = 0; w2 < (tid >> 6); ++w2) woff += sh.sel.wsum[w2];
                unsigned excl = woff + inc - s;
                if (rank >= excl && rank < excl + s) {   // exactly one thread
                    unsigned run = excl, binSel = basebin;
                    for (unsigned j = 0; j < cpl; ++j) {
                        unsigned h = sh.sel.hist[basebin + j];
                        if (run + h > rank) { binSel = basebin + j; break; }
                        run += h;
                    }
                    sh.sel.sres[0] = binSel; sh.sel.sres[1] = rank - run;
                }
                __syncthreads();
                selkey = (selkey << w) | sh.sel.sres[0];
                rank = sh.sel.sres[1];
                __syncthreads();
            }
            if (tid == 0) st_dev(&norm[blk], fmaxf(fabsf(key2f(selkey)), EPSF));
        }
        if (tid == 0) {
            __asm__ volatile("s_waitcnt vmcnt(0)" ::: "memory");  // norm/cnt at LLC
            __hip_atomic_fetch_add(ctrB, 1u, __ATOMIC_RELAXED, __HIP_MEMORY_SCOPE_AGENT);
        }
    }

    // ================= Barrier: all 256 norms published =================
    if (tid == 0) {
        while (ld_dev(ctrB) < (unsigned)NBG) __builtin_amdgcn_s_sleep(32);
    }
    __syncthreads();

    // ================= Phase L: loss (all 1024 blocks, 8 pts/thread) =================
    int b = blk >> 6;
    if (tid < NGROUP) sh.misc.sinv[tid] = 1.0f / ld_dev(&norm[(b << 4) + tid]);
    __syncthreads();
    int p0 = b * NPTS_N + (blk & 63) * 2048 + tid * 8;
    unsigned long long pk64 = *(const unsigned long long*)(packed + p0);
    const float4* pr4 = (const float4*)(pred + (size_t)p0 * 3);
    const float4* tg4 = (const float4*)(target + (size_t)p0 * 3);
    float pv[24], tv[24];
    #pragma unroll
    for (int k = 0; k < 6; ++k) { *(float4*)(pv + 4 * k) = pr4[k]; *(float4*)(tv + 4 * k) = tg4[k]; }
    float acc = 0.f;
    #pragma unroll
    for (int q = 0; q < 8; ++q) {
        unsigned byte = (unsigned)(pk64 >> (8 * q)) & 0xFFu;
        if (byte & 0x80u) {
            float inv = sh.misc.sinv[byte & 15u];
            #pragma unroll
            for (int c = 0; c < 3; ++c) {
                float pp = pv[q * 3 + c] * inv;
                float tt = tv[q * 3 + c] * inv;
                float lp = copysignf(flog1p(fabsf(pp)), pp);
                float lt = copysignf(flog1p(fabsf(tt)), tt);
                acc += fabsf(lp - lt);
            }
        }
    }
    #pragma unroll
    for (int off = 32; off; off >>= 1) acc += __shfl_down(acc, off, 64);
    if ((tid & 63) == 0) sh.misc.swsum[tid >> 6] = acc;
    __syncthreads();
    if (tid == 0) {
        float v = sh.misc.swsum[0] + sh.misc.swsum[1] + sh.misc.swsum[2] + sh.misc.swsum[3];
        atomicAdd(&accF[blk & (NACC - 1)], v);   // relaxed coherence-point add
        __asm__ volatile("s_waitcnt vmcnt(0)" ::: "memory");  // my add is at LLC
        unsigned old = __hip_atomic_fetch_add(done, 1u, __ATOMIC_RELAXED,
                                              __HIP_MEMORY_SCOPE_AGENT);
        sh.misc.isLast = (old == (unsigned)(LGRID - 1));
    }
    __syncthreads();
    if (sh.misc.isLast) {
        float s = 0.f;
        if (tid < NACC) s = ld_dev(&accF[tid]);
        #pragma unroll
        for (int off = 32; off; off >>= 1) s += __shfl_down(s, off, 64);
        if (tid == 0) sh.misc.accSum = s;
        sh.misc.red[tid] = (float)ld_dev(&cnt[tid]);
        __syncthreads();
        for (int st = 128; st; st >>= 1) {
            if (tid < st) sh.misc.red[tid] += sh.misc.red[tid + st];
            __syncthreads();
        }
        if (tid == 0) out[0] = sh.misc.accSum / (3.0f * sh.misc.red[0] + 1e-6f);
    }
}

extern "C" void kernel_launch(void* const* d_in, const int* in_sizes, int n_in,
                              void* d_out, int out_size, void* d_ws, size_t ws_size,
                              hipStream_t stream) {
    const float* pred   = (const float*)d_in[0];
    const float* target = (const float*)d_in[1];
    const int*   mask   = (const int*)d_in[2];
    const int*   groups = (const int*)d_in[3];
    float* out = (float*)d_out;

    char* ws = (char*)d_ws;
    const size_t MB = 1024 * 1024;
    unsigned*      bucket   = (unsigned*)ws;                          // 8 MB
    unsigned char* packed   = (unsigned char*)(ws + 8 * MB);          // 2 MB
    unsigned*      blockCnt = (unsigned*)(ws + 10 * MB);              // 32 KB
    unsigned*      cnt      = (unsigned*)(ws + 10 * MB + 32768);      // 1 KB
    float*         normv    = (float*)(ws + 10 * MB + 32768 + 1024);  // 1 KB
    float*         accF     = (float*)(ws + 10 * MB + 32768 + 2048);  // 256 B
    unsigned*      done     = (unsigned*)(ws + 10 * MB + 32768 + 3072);
    unsigned*      ctrB     = (unsigned*)(ws + 10 * MB + 32768 + 3072 + 64);

    compact_kernel<<<dim3(CBLK), dim3(256), 0, stream>>>(
        target, mask, groups, bucket, blockCnt, packed, accF, done, ctrB);
    sel_loss_kernel<<<dim3(LGRID), dim3(256), 0, stream>>>(
        pred, target, packed, bucket, blockCnt, cnt, normv, accF, done, ctrB, out);
}

// Round 13
// 133.464 us; speedup vs baseline: 1.1138x; 1.1138x over previous
//
#include <hip/hip_runtime.h>
#include <math.h>

// Problem constants: B=16, N=131072, NUM_GROUPS=16
#define NPTS_N 131072
#define NGROUP 16
#define NBG 256            // B * NUM_GROUPS
#define CBLK 512           // compact blocks (32 per batch)  [R8-proven geometry]
#define BPB 32             // compact blocks per batch
#define PPB 4096           // points per compact block
#define SEGCAP 256         // per (block,group) segment cap; mean 128, sigma ~11
#define SK2CAP 2048        // LDS cap for keys surviving pass 1 (typ. < 100)
#define NACC 64            // spread accumulator slots for loss sum
#define LGRID 1024         // loss blocks (2048 pts each)
#define EPSF 1e-6f

// ---------- order-preserving float<->uint key ----------
__device__ __forceinline__ unsigned f2key(float f) {
    unsigned u = __float_as_uint(f);
    return (u & 0x80000000u) ? ~u : (u | 0x80000000u);
}
__device__ __forceinline__ float key2f(unsigned k) {
    unsigned u = (k & 0x80000000u) ? (k ^ 0x80000000u) : ~k;
    return __uint_as_float(u);
}
__device__ __forceinline__ float flog1p(float a) {
    return __log2f(1.0f + a) * 0.69314718056f;
}

// ---------- 1) compact valid z-keys + emit packed mask|group bytes ----------
// [byte-identical to R8's proven kernel]
__global__ __launch_bounds__(256) void compact_kernel(
        const float* __restrict__ target,
        const int* __restrict__ mask,
        const int* __restrict__ groups,
        unsigned* __restrict__ bucket,
        unsigned* __restrict__ blockCnt,
        unsigned char* __restrict__ packed) {
    __shared__ unsigned scnt[NGROUP];
    int tid = threadIdx.x, blk = blockIdx.x;
    int i0 = blk * PPB + tid * 16;      // 16 consecutive points per thread
    if (tid < NGROUP) scnt[tid] = 0;
    __syncthreads();
    int4 m[4], g[4];
    #pragma unroll
    for (int k = 0; k < 4; ++k) {
        m[k] = *(const int4*)(mask + i0 + k * 4);
        g[k] = *(const int4*)(groups + i0 + k * 4);
    }
    unsigned pk[4];
    unsigned keys[16]; unsigned meta[16]; unsigned vbits = 0;
    #pragma unroll
    for (int k = 0; k < 4; ++k) {
        int mm[4] = {m[k].x, m[k].y, m[k].z, m[k].w};
        int gg[4] = {g[k].x, g[k].y, g[k].z, g[k].w};
        unsigned pb = 0;
        #pragma unroll
        for (int j = 0; j < 4; ++j) {
            int idx = k * 4 + j;
            unsigned gj = (unsigned)gg[j] & 15u;
            pb |= (gj | (mm[j] ? 0x80u : 0u)) << (8 * j);
            if (mm[j]) {
                keys[idx] = f2key(target[(size_t)(i0 + idx) * 3 + 2]);
                unsigned pos = atomicAdd(&scnt[gj], 1u);   // LDS atomic
                meta[idx] = (gj << 16) | pos;
                vbits |= 1u << idx;
            }
        }
        pk[k] = pb;
    }
    *(uint4*)(packed + i0) = make_uint4(pk[0], pk[1], pk[2], pk[3]);
    __syncthreads();
    if (tid < NGROUP) blockCnt[blk * NGROUP + tid] = scnt[tid];  // plain store
    #pragma unroll
    for (int idx = 0; idx < 16; ++idx) {
        if (vbits & (1u << idx)) {
            unsigned gj = meta[idx] >> 16, pos = meta[idx] & 0xFFFFu;
            if (pos < SEGCAP)
                bucket[(size_t)(blk * NGROUP + gj) * SEGCAP + pos] = keys[idx];
        }
    }
}

// ---------- 2) per-(b,g) exact lower-median: staging-free radix select ----------
// one block (256 threads) per (b,g). Pass 1 histograms straight from global
// (16 KB once); survivors of the selected 11-bit prefix (typ. <100 keys, since
// N(0,1) float keys near the median have fine-grained prefixes) collected into
// a small LDS buffer for passes 2-3. Global-reread fallback if (impossibly)
// >SK2CAP survive. Block 0 also zero-inits loss accumulators.
__global__ __launch_bounds__(256) void select_kernel(
        const unsigned* __restrict__ bucket,
        const unsigned* __restrict__ blockCnt,
        float* __restrict__ norm,
        unsigned* __restrict__ cnt,
        float* __restrict__ accF,
        unsigned* __restrict__ done) {
    __shared__ unsigned hist[2048];      // 8 KB
    __shared__ unsigned skey2[SK2CAP];   // 8 KB
    __shared__ unsigned sc[BPB];
    __shared__ unsigned wsum[4];
    __shared__ unsigned sres[2];
    __shared__ unsigned sn[2];
    __shared__ unsigned m2;
    int bg = blockIdx.x, tid = threadIdx.x;
    int b = bg >> 4, g = bg & 15;
    int wv = tid >> 6, ln = tid & 63;
    if (bg == 0) {                       // init for fused loss finalize
        if (tid < NACC) accF[tid] = 0.f;
        if (tid == NACC) *done = 0;
    }
    if (tid < BPB) sc[tid] = blockCnt[(b * BPB + tid) * NGROUP + g];
    __syncthreads();
    if (tid == 0) {
        unsigned ntrue = 0, ncap = 0;
        for (int c = 0; c < BPB; ++c) {
            unsigned s = sc[c];
            ntrue += s;
            ncap += (s > SEGCAP ? SEGCAP : s);
        }
        sn[0] = ntrue; sn[1] = ncap;
        cnt[bg] = ntrue;                 // true valid count (denominator)
    }
    __syncthreads();
    unsigned n = sn[1];
    if (n == 0) { if (tid == 0) norm[bg] = 1.0f; return; }

    unsigned rank = (n - 1) >> 1;        // lower-median rank
    unsigned selkey = 0;
    unsigned m2cnt = 0; bool ovf = false;
    const int shifts[3] = {21, 10, 0};
    const int widths[3] = {11, 11, 10};
    for (int p = 0; p < 3; ++p) {
        int sft = shifts[p], w = widths[p];
        unsigned nb = 1u << w, bmask = nb - 1;
        for (unsigned j = tid; j < nb; j += 256) hist[j] = 0;
        __syncthreads();
        if (p == 0) {
            // wave wv histograms segments wv*8 .. wv*8+7 straight from global
            for (int c = wv * 8; c < wv * 8 + 8; ++c) {
                unsigned count = sc[c]; if (count > SEGCAP) count = SEGCAP;
                const unsigned* src = bucket + (size_t)((b * BPB + c) * NGROUP + g) * SEGCAP;
                for (unsigned j = ln; j < count; j += 64)
                    atomicAdd(&hist[src[j] >> 21], 1u);
            }
        } else if (!ovf) {
            for (unsigned j = tid; j < m2cnt; j += 256) {
                unsigned key = skey2[j];
                bool in = (p == 1) || ((key >> 10) == selkey);
                if (in) atomicAdd(&hist[(key >> sft) & bmask], 1u);
            }
        } else {  // fallback: re-read global with prefix filter (never expected)
            for (int c = wv * 8; c < wv * 8 + 8; ++c) {
                unsigned count = sc[c]; if (count > SEGCAP) count = SEGCAP;
                const unsigned* src = bucket + (size_t)((b * BPB + c) * NGROUP + g) * SEGCAP;
                for (unsigned j = ln; j < count; j += 64) {
                    unsigned key = src[j];
                    if ((key >> (sft + w)) == selkey)
                        atomicAdd(&hist[(key >> sft) & bmask], 1u);
                }
            }
        }
        __syncthreads();
        unsigned cpl = nb >> 8;          // bins per thread: 8 or 4
        unsigned basebin = tid * cpl;
        unsigned s = 0;
        for (unsigned j = 0; j < cpl; ++j) s += hist[basebin + j];
        unsigned inc = s;
        #pragma unroll
        for (int o = 1; o < 64; o <<= 1) {
            unsigned v = __shfl_up(inc, o, 64);
            if ((tid & 63) >= o) inc += v;
        }
        if ((tid & 63) == 63) wsum[tid >> 6] = inc;
        __syncthreads();
        unsigned woff = 0;
        for (int w2 = 0; w2 < (tid >> 6); ++w2) woff += wsum[w2];
        unsigned excl = woff + inc - s;
        if (rank >= excl && rank < excl + s) {   // exactly one thread
            unsigned run = excl, binSel = basebin;
            for (unsigned j = 0; j < cpl; ++j) {
                unsigned h = hist[basebin + j];
                if (run + h > rank) { binSel = basebin + j; break; }
                run += h;
            }
            sres[0] = binSel; sres[1] = rank - run;
        }
        __syncthreads();
        selkey = (selkey << w) | sres[0];
        rank = sres[1];
        __syncthreads();
        if (p == 0) {
            // collect keys matching the selected 11-bit prefix into LDS
            if (tid == 0) m2 = 0;
            __syncthreads();
            for (int c = wv * 8; c < wv * 8 + 8; ++c) {
                unsigned count = sc[c]; if (count > SEGCAP) count = SEGCAP;
                const unsigned* src = bucket + (size_t)((b * BPB + c) * NGROUP + g) * SEGCAP;
                for (unsigned j = ln; j < count; j += 64) {
                    unsigned key = src[j];            // L2-warm re-read
                    if ((key >> 21) == selkey) {
                        unsigned pos = atomicAdd(&m2, 1u);
                        if (pos < SK2CAP) skey2[pos] = key;
                    }
                }
            }
            __syncthreads();
            m2cnt = m2;
            ovf = (m2cnt > SK2CAP);
            if (ovf) m2cnt = 0;
            __syncthreads();
        }
    }
    if (tid == 0) norm[bg] = fmaxf(fabsf(key2f(selkey)), EPSF);
}

// ---------- 3) loss pass + ordering-free fused finalize ----------
// [byte-identical to R8's proven kernel]
__global__ __launch_bounds__(256) void loss_kernel(
        const float* __restrict__ pred,
        const float* __restrict__ target,
        const unsigned char* __restrict__ packed,
        const float* __restrict__ norm,
        const unsigned* __restrict__ cnt,
        float* __restrict__ accF,
        unsigned* __restrict__ done,
        float* __restrict__ out) {
    __shared__ float sinv[NGROUP];
    __shared__ float swsum[4];
    __shared__ bool isLast;
    __shared__ float red[256];
    __shared__ float accSum;
    int tid = threadIdx.x;
    int blk = blockIdx.x;
    int b = blk >> 6;
    if (tid < NGROUP) sinv[tid] = 1.0f / norm[(b << 4) + tid];
    __syncthreads();
    int p0 = b * NPTS_N + (blk & 63) * 2048 + tid * 8;
    unsigned long long pk64 = *(const unsigned long long*)(packed + p0);
    const float4* pr4 = (const float4*)(pred + (size_t)p0 * 3);
    const float4* tg4 = (const float4*)(target + (size_t)p0 * 3);
    float pv[24], tv[24];
    #pragma unroll
    for (int k = 0; k < 6; ++k) { *(float4*)(pv + 4 * k) = pr4[k]; *(float4*)(tv + 4 * k) = tg4[k]; }
    float acc = 0.f;
    #pragma unroll
    for (int q = 0; q < 8; ++q) {
        unsigned byte = (unsigned)(pk64 >> (8 * q)) & 0xFFu;
        if (byte & 0x80u) {
            float inv = sinv[byte & 15u];
            #pragma unroll
            for (int c = 0; c < 3; ++c) {
                float pp = pv[q * 3 + c] * inv;
                float tt = tv[q * 3 + c] * inv;
                float lp = copysignf(flog1p(fabsf(pp)), pp);
                float lt = copysignf(flog1p(fabsf(tt)), tt);
                acc += fabsf(lp - lt);
            }
        }
    }
    #pragma unroll
    for (int off = 32; off; off >>= 1) acc += __shfl_down(acc, off, 64);
    if ((tid & 63) == 0) swsum[tid >> 6] = acc;
    __syncthreads();
    if (tid == 0) {
        float v = swsum[0] + swsum[1] + swsum[2] + swsum[3];
        atomicAdd(&accF[blk & (NACC - 1)], v);   // relaxed, coherence-point add
        __asm__ volatile("s_waitcnt vmcnt(0)" ::: "memory");  // my add is at LLC
        unsigned old = __hip_atomic_fetch_add(done, 1u, __ATOMIC_RELAXED,
                                              __HIP_MEMORY_SCOPE_AGENT);
        isLast = (old == (unsigned)(LGRID - 1));
    }
    __syncthreads();
    if (isLast) {
        float s = 0.f;
        if (tid < NACC)
            s = __hip_atomic_load(&accF[tid], __ATOMIC_RELAXED, __HIP_MEMORY_SCOPE_AGENT);
        #pragma unroll
        for (int off = 32; off; off >>= 1) s += __shfl_down(s, off, 64);
        if (tid == 0) accSum = s;
        red[tid] = (float)cnt[tid];              // written by select dispatch
        __syncthreads();
        for (int st = 128; st; st >>= 1) {
            if (tid < st) red[tid] += red[tid + st];
            __syncthreads();
        }
        if (tid == 0) out[0] = accSum / (3.0f * red[0] + 1e-6f);
    }
}

extern "C" void kernel_launch(void* const* d_in, const int* in_sizes, int n_in,
                              void* d_out, int out_size, void* d_ws, size_t ws_size,
                              hipStream_t stream) {
    const float* pred   = (const float*)d_in[0];
    const float* target = (const float*)d_in[1];
    const int*   mask   = (const int*)d_in[2];
    const int*   groups = (const int*)d_in[3];
    float* out = (float*)d_out;

    char* ws = (char*)d_ws;
    const size_t MB = 1024 * 1024;
    unsigned*      bucket   = (unsigned*)ws;                          // 8 MB
    unsigned char* packed   = (unsigned char*)(ws + 8 * MB);          // 2 MB
    unsigned*      blockCnt = (unsigned*)(ws + 10 * MB);              // 32 KB
    unsigned*      cnt      = (unsigned*)(ws + 10 * MB + 32768);      // 1 KB
    float*         normv    = (float*)(ws + 10 * MB + 32768 + 1024);  // 1 KB
    float*         accF     = (float*)(ws + 10 * MB + 32768 + 2048);  // 256 B
    unsigned*      done     = (unsigned*)(ws + 10 * MB + 32768 + 3072);

    compact_kernel<<<dim3(CBLK), dim3(256), 0, stream>>>(target, mask, groups,
                                                         bucket, blockCnt, packed);
    select_kernel<<<dim3(NBG), dim3(256), 0, stream>>>(bucket, blockCnt, normv,
                                                       cnt, accF, done);
    loss_kernel<<<dim3(LGRID), dim3(256), 0, stream>>>(pred, target, packed, normv,
                                                       cnt, accF, done, out);
}